// Round 4
// baseline (1101.784 us; speedup 1.0000x reference)
//
#include <hip/hip_runtime.h>
#include <cmath>

// Problem constants (from reference): N=16384, T=256, K=8, P_DYN=16, P_STAT=8, S=4
constexpr int N_ = 16384;
constexpr int T_ = 256;
constexpr int K_ = 8;
constexpr int PD_ = 16;
constexpr int PS_ = 8;
constexpr int S_ = 4;

// clang ext_vector type: __builtin_nontemporal_store accepts this (it rejects
// HIP's float4, which is a class type).
typedef float f32x4 __attribute__((ext_vector_type(4)));

// -----------------------------------------------------------------------------
// Kernel 1: compute the time-varying drive
//   c[n*T + t] = dot(A[n,t,:],gA) + dot(L[n,t,:],gL) + dot(V[n,:],gV)
//               + (t==0 ? mu_init : alpha * Y[n, t-1])
// Thread g = n*T + t  -> A/L reads are contiguous float4 across the wave,
// c write is perfectly coalesced. V/gammas are tiny (L1/L2-resident).
// -----------------------------------------------------------------------------
__global__ __launch_bounds__(256) void k_drive(
    const float* __restrict__ A, const float* __restrict__ L,
    const float* __restrict__ V, const float* __restrict__ Y,
    const float* __restrict__ gA, const float* __restrict__ gLw,
    const float* __restrict__ gVw, const float* __restrict__ alpha_,
    const float* __restrict__ mu_init_, float* __restrict__ c)
{
    const int g = blockIdx.x * 256 + threadIdx.x;   // g = n*T + t
    const int t = g & (T_ - 1);
    const int n = g >> 8;                           // T_ == 256

    const float4* A4 = (const float4*)(A + (size_t)g * K_);
    const float4  a0 = A4[0], a1 = A4[1];
    const float4* L4 = (const float4*)(L + (size_t)g * PD_);
    const float4  l0 = L4[0], l1 = L4[1], l2 = L4[2], l3 = L4[3];
    const float4* V4 = (const float4*)(V + (size_t)n * PS_);
    const float4  w0 = V4[0], w1 = V4[1];

    float b = 0.f;
    b += a0.x * gA[0] + a0.y * gA[1] + a0.z * gA[2] + a0.w * gA[3];
    b += a1.x * gA[4] + a1.y * gA[5] + a1.z * gA[6] + a1.w * gA[7];

    b += l0.x * gLw[0]  + l0.y * gLw[1]  + l0.z * gLw[2]  + l0.w * gLw[3];
    b += l1.x * gLw[4]  + l1.y * gLw[5]  + l1.z * gLw[6]  + l1.w * gLw[7];
    b += l2.x * gLw[8]  + l2.y * gLw[9]  + l2.z * gLw[10] + l2.w * gLw[11];
    b += l3.x * gLw[12] + l3.y * gLw[13] + l3.z * gLw[14] + l3.w * gLw[15];

    b += w0.x * gVw[0] + w0.y * gVw[1] + w0.z * gVw[2] + w0.w * gVw[3];
    b += w1.x * gVw[4] + w1.y * gVw[5] + w1.z * gVw[6] + w1.w * gVw[7];

    const float extra = (t == 0) ? mu_init_[0] : (alpha_[0] * Y[g - 1]);
    c[g] = b + extra;
}

// -----------------------------------------------------------------------------
// Kernel 2: per-(s,n) linear scan over T, chunked by 16 with double-buffered
// prefetch. lv is a constant fill. All per-thread arrays are compile-time
// indexed (no scratch).
// -----------------------------------------------------------------------------
__device__ __forceinline__ void load_chunk(const float* __restrict__ cp,
                                           const float* __restrict__ ep,
                                           int j, float (&cc)[16], float (&ee)[16])
{
    const float4* c4 = (const float4*)(cp + j * 16);
#pragma unroll
    for (int q = 0; q < 4; ++q) {
        const float4 v = c4[q];
        cc[q * 4 + 0] = v.x; cc[q * 4 + 1] = v.y;
        cc[q * 4 + 2] = v.z; cc[q * 4 + 3] = v.w;
    }
#pragma unroll
    for (int i = 0; i < 16; ++i)
        ee[i] = ep[(size_t)(j * 16 + i) * N_];
}

__device__ __forceinline__ void nt_store4(float* p, float a, float b,
                                          float cc, float d)
{
    f32x4 v;
    v.x = a; v.y = b; v.z = cc; v.w = d;
    __builtin_nontemporal_store(v, (f32x4*)p);
}

__device__ __forceinline__ void proc_chunk(
    int j, bool first, float psi, float sig, float sig0, float v0, float v1,
    const float (&cc)[16], const float (&ee)[16],
    float& Z, float* __restrict__ Zp, float* __restrict__ Mp,
    float* __restrict__ Vp)
{
    float zr[16], mr[16];
#pragma unroll
    for (int i = 0; i < 16; ++i) {
        float mu, z;
        if (i == 0 && first) {
            mu = cc[0];                 // mu0 = mu_init + base (already in c)
            z  = mu + sig0 * ee[0];     // Z0 = mu0 + sigma0*eps0
        } else {
            mu = psi * Z + cc[i];
            z  = mu + sig * ee[i];
        }
        Z = z;
        zr[i] = z;
        mr[i] = mu;
    }
#pragma unroll
    for (int q = 0; q < 4; ++q) {
        nt_store4(Zp + j * 16 + q * 4,
                  zr[q * 4], zr[q * 4 + 1], zr[q * 4 + 2], zr[q * 4 + 3]);
        nt_store4(Mp + j * 16 + q * 4,
                  mr[q * 4], mr[q * 4 + 1], mr[q * 4 + 2], mr[q * 4 + 3]);
        const float lvx = (first && q == 0) ? v0 : v1;  // t==0 uses 2*lsig0
        nt_store4(Vp + j * 16 + q * 4, lvx, v1, v1, v1);
    }
}

__global__ __launch_bounds__(256) void k_scan(
    const float* __restrict__ c, const float* __restrict__ eps,
    const float* __restrict__ psi_, const float* __restrict__ lsig_,
    const float* __restrict__ lsig0_, float* __restrict__ out)
{
    const int nn = threadIdx.x & 63;
    const int s  = threadIdx.x >> 6;
    const int n  = blockIdx.x * 64 + nn;

    const float psi  = psi_[0];
    const float ls   = lsig_[0];
    const float ls0  = lsig0_[0];
    const float sig  = expf(ls);
    const float sig0 = expf(ls0);
    const float v0   = 2.f * ls0;
    const float v1   = 2.f * ls;

    const float* cp = c + (size_t)n * T_;
    const float* ep = eps + (size_t)s * ((size_t)T_ * N_) + n;
    const size_t SNT = (size_t)S_ * N_ * T_;
    float* Zp = out + ((size_t)s * N_ + n) * T_;
    float* Mp = Zp + SNT;
    float* Vp = Zp + 2 * SNT;

    float cA[16], eA[16], cB[16], eB[16];
    float Z = 0.f;

    load_chunk(cp, ep, 0, cA, eA);
    for (int j = 0; j < 16; j += 2) {
        load_chunk(cp, ep, j + 1, cB, eB);                 // prefetch odd chunk
        proc_chunk(j, j == 0, psi, sig, sig0, v0, v1, cA, eA, Z, Zp, Mp, Vp);
        if (j + 2 < 16)
            load_chunk(cp, ep, j + 2, cA, eA);             // prefetch next even
        proc_chunk(j + 1, false, psi, sig, sig0, v0, v1, cB, eB, Z, Zp, Mp, Vp);
    }
}

// -----------------------------------------------------------------------------
extern "C" void kernel_launch(void* const* d_in, const int* in_sizes, int n_in,
                              void* d_out, int out_size, void* d_ws, size_t ws_size,
                              hipStream_t stream)
{
    const float* A     = (const float*)d_in[0];
    const float* L     = (const float*)d_in[1];
    const float* V     = (const float*)d_in[2];
    const float* Y     = (const float*)d_in[3];
    const float* eps   = (const float*)d_in[4];
    const float* psi   = (const float*)d_in[5];
    const float* gA    = (const float*)d_in[6];
    const float* gLw   = (const float*)d_in[7];
    const float* gVw   = (const float*)d_in[8];
    const float* alpha = (const float*)d_in[9];
    const float* lsig  = (const float*)d_in[10];
    const float* mu_i  = (const float*)d_in[11];
    const float* lsig0 = (const float*)d_in[12];

    float* out = (float*)d_out;
    float* c   = (float*)d_ws;   // N*T floats = 16.8 MB workspace

    k_drive<<<(N_ * T_) / 256, 256, 0, stream>>>(A, L, V, Y, gA, gLw, gVw,
                                                 alpha, mu_i, c);
    k_scan<<<N_ / 64, 256, 0, stream>>>(c, eps, psi, lsig, lsig0, out);
}

// Round 5
// 589.778 us; speedup vs baseline: 1.8681x; 1.8681x over previous
//
#include <hip/hip_runtime.h>
#include <cmath>

// Problem constants (from reference): N=16384, T=256, K=8, P_DYN=16, P_STAT=8, S=4
constexpr int N_ = 16384;
constexpr int T_ = 256;
constexpr int K_ = 8;
constexpr int PD_ = 16;
constexpr int PS_ = 8;
constexpr int S_ = 4;

// clang ext_vector type: __builtin_nontemporal_store accepts this (it rejects
// HIP's float4, which is a class type).
typedef float f32x4 __attribute__((ext_vector_type(4)));

// -----------------------------------------------------------------------------
// Kernel 1: time-varying drive
//   c[n*T + t] = dot(A[n,t,:],gA) + dot(L[n,t,:],gL) + dot(V[n,:],gV)
//               + (t==0 ? mu_init : alpha * Y[n, t-1])
// -----------------------------------------------------------------------------
__global__ __launch_bounds__(256) void k_drive(
    const float* __restrict__ A, const float* __restrict__ L,
    const float* __restrict__ V, const float* __restrict__ Y,
    const float* __restrict__ gA, const float* __restrict__ gLw,
    const float* __restrict__ gVw, const float* __restrict__ alpha_,
    const float* __restrict__ mu_init_, float* __restrict__ c)
{
    const int g = blockIdx.x * 256 + threadIdx.x;   // g = n*T + t
    const int t = g & (T_ - 1);
    const int n = g >> 8;                           // T_ == 256

    const float4* A4 = (const float4*)(A + (size_t)g * K_);
    const float4  a0 = A4[0], a1 = A4[1];
    const float4* L4 = (const float4*)(L + (size_t)g * PD_);
    const float4  l0 = L4[0], l1 = L4[1], l2 = L4[2], l3 = L4[3];
    const float4* V4 = (const float4*)(V + (size_t)n * PS_);
    const float4  w0 = V4[0], w1 = V4[1];

    float b = 0.f;
    b += a0.x * gA[0] + a0.y * gA[1] + a0.z * gA[2] + a0.w * gA[3];
    b += a1.x * gA[4] + a1.y * gA[5] + a1.z * gA[6] + a1.w * gA[7];

    b += l0.x * gLw[0]  + l0.y * gLw[1]  + l0.z * gLw[2]  + l0.w * gLw[3];
    b += l1.x * gLw[4]  + l1.y * gLw[5]  + l1.z * gLw[6]  + l1.w * gLw[7];
    b += l2.x * gLw[8]  + l2.y * gLw[9]  + l2.z * gLw[10] + l2.w * gLw[11];
    b += l3.x * gLw[12] + l3.y * gLw[13] + l3.z * gLw[14] + l3.w * gLw[15];

    b += w0.x * gVw[0] + w0.y * gVw[1] + w0.z * gVw[2] + w0.w * gVw[3];
    b += w1.x * gVw[4] + w1.y * gVw[5] + w1.z * gVw[6] + w1.w * gVw[7];

    const float extra = (t == 0) ? mu_init_[0] : (alpha_[0] * Y[g - 1]);
    c[g] = b + extra;
}

// -----------------------------------------------------------------------------
// Kernel 2: lv plane fill. lv[s,n,0] = 2*lsig0, lv[s,n,1..T-1] = 2*lsig.
// Pure streaming full-line nt stores.
// -----------------------------------------------------------------------------
__global__ __launch_bounds__(256) void k_fill_lv(
    const float* __restrict__ lsig_, const float* __restrict__ lsig0_,
    float* __restrict__ lv)
{
    const size_t i = (size_t)blockIdx.x * 256 + threadIdx.x;  // float4 index
    const float v1 = 2.f * lsig_[0];
    f32x4 v; v.x = v1; v.y = v1; v.z = v1; v.w = v1;
    if ((i & (T_ / 4 - 1)) == 0) v.x = 2.f * lsig0_[0];       // t==0 of each row
    __builtin_nontemporal_store(v, (f32x4*)lv + i);
}

// -----------------------------------------------------------------------------
// Kernel 3: per-(s,n) linear scan over T, chunked by 16, double-buffered
// prefetch, LDS-transposed FULL-LINE output stores (4 lanes cover one chain's
// 64B line). Raw s_barrier + lgkmcnt-only waits keep prefetch loads and nt
// stores in flight across barriers (no vmcnt drain).
// -----------------------------------------------------------------------------
__device__ __forceinline__ void load_chunk(const float* __restrict__ cp,
                                           const float* __restrict__ ep,
                                           int j, float (&cc)[16], float (&ee)[16])
{
    const float4* c4 = (const float4*)(cp + j * 16);
#pragma unroll
    for (int q = 0; q < 4; ++q) {
        const float4 v = c4[q];
        cc[q * 4 + 0] = v.x; cc[q * 4 + 1] = v.y;
        cc[q * 4 + 2] = v.z; cc[q * 4 + 3] = v.w;
    }
#pragma unroll
    for (int i = 0; i < 16; ++i)
        ee[i] = ep[(size_t)(j * 16 + i) * N_];
}

__device__ __forceinline__ void do_chunk(
    int j, bool first, float psi, float sig, float sig0,
    const float (&cc)[16], const float (&ee)[16], float& Z,
    float* zl, float* ml, int tid, int nb, float* __restrict__ out)
{
    float zr[16], mr[16];
#pragma unroll
    for (int i = 0; i < 16; ++i) {
        float mu, z;
        if (i == 0 && first) {
            mu = cc[0];                 // mu0 = mu_init + base (already in c)
            z  = mu + sig0 * ee[0];     // Z0 = mu0 + sigma0*eps0
        } else {
            mu = psi * Z + cc[i];
            z  = mu + sig * ee[i];
        }
        Z = z; zr[i] = z; mr[i] = mu;
    }
    // stage this chunk's 16 t-values per chain into LDS (stride 17: 2-way = free)
#pragma unroll
    for (int e = 0; e < 16; ++e) {
        zl[tid * 17 + e] = zr[e];
        ml[tid * 17 + e] = mr[e];
    }
    // barrier A: only LDS writes must be visible; keep vmcnt in flight
    asm volatile("s_waitcnt lgkmcnt(0)" ::: "memory");
    __builtin_amdgcn_s_barrier();
    __builtin_amdgcn_sched_barrier(0);

    // cooperative store: thread (ch=tid>>2, qq=tid&3) writes 16B of chain ch's
    // 64B line; a wave covers 16 complete cache lines. 4 rounds cover 256 chains.
    const int cq = tid >> 2;
    const int qq = tid & 3;
    const size_t SNT = (size_t)S_ * N_ * T_;
#pragma unroll
    for (int r = 0; r < 4; ++r) {
        const int ch = r * 64 + cq;
        const int ss = ch >> 6;
        const int nc = nb + (ch & 63);
        float* rowZ = out + ((size_t)ss * N_ + nc) * T_ + j * 16 + qq * 4;
        f32x4 vz, vm;
        vz.x = zl[ch * 17 + qq * 4 + 0]; vz.y = zl[ch * 17 + qq * 4 + 1];
        vz.z = zl[ch * 17 + qq * 4 + 2]; vz.w = zl[ch * 17 + qq * 4 + 3];
        vm.x = ml[ch * 17 + qq * 4 + 0]; vm.y = ml[ch * 17 + qq * 4 + 1];
        vm.z = ml[ch * 17 + qq * 4 + 2]; vm.w = ml[ch * 17 + qq * 4 + 3];
        __builtin_nontemporal_store(vz, (f32x4*)rowZ);
        __builtin_nontemporal_store(vm, (f32x4*)(rowZ + SNT));
    }
    // barrier B: LDS reads must complete before next chunk overwrites
    asm volatile("s_waitcnt lgkmcnt(0)" ::: "memory");
    __builtin_amdgcn_s_barrier();
    __builtin_amdgcn_sched_barrier(0);
}

__global__ __launch_bounds__(256) void k_scan(
    const float* __restrict__ c, const float* __restrict__ eps,
    const float* __restrict__ psi_, const float* __restrict__ lsig_,
    const float* __restrict__ lsig0_, float* __restrict__ out)
{
    __shared__ float zl[256 * 17];
    __shared__ float ml[256 * 17];

    const int tid = threadIdx.x;
    const int nn  = tid & 63;
    const int s   = tid >> 6;
    const int nb  = blockIdx.x * 64;
    const int n   = nb + nn;

    const float psi  = psi_[0];
    const float sig  = expf(lsig_[0]);
    const float sig0 = expf(lsig0_[0]);

    const float* cp = c + (size_t)n * T_;
    const float* ep = eps + (size_t)s * ((size_t)T_ * N_) + n;

    float cA[16], eA[16], cB[16], eB[16];
    float Z = 0.f;

    load_chunk(cp, ep, 0, cA, eA);
    for (int j = 0; j < 16; j += 2) {
        load_chunk(cp, ep, j + 1, cB, eB);                 // prefetch odd chunk
        do_chunk(j, j == 0, psi, sig, sig0, cA, eA, Z, zl, ml, tid, nb, out);
        if (j + 2 < 16)
            load_chunk(cp, ep, j + 2, cA, eA);             // prefetch next even
        do_chunk(j + 1, false, psi, sig, sig0, cB, eB, Z, zl, ml, tid, nb, out);
    }
}

// -----------------------------------------------------------------------------
extern "C" void kernel_launch(void* const* d_in, const int* in_sizes, int n_in,
                              void* d_out, int out_size, void* d_ws, size_t ws_size,
                              hipStream_t stream)
{
    const float* A     = (const float*)d_in[0];
    const float* L     = (const float*)d_in[1];
    const float* V     = (const float*)d_in[2];
    const float* Y     = (const float*)d_in[3];
    const float* eps   = (const float*)d_in[4];
    const float* psi   = (const float*)d_in[5];
    const float* gA    = (const float*)d_in[6];
    const float* gLw   = (const float*)d_in[7];
    const float* gVw   = (const float*)d_in[8];
    const float* alpha = (const float*)d_in[9];
    const float* lsig  = (const float*)d_in[10];
    const float* mu_i  = (const float*)d_in[11];
    const float* lsig0 = (const float*)d_in[12];

    float* out = (float*)d_out;
    float* c   = (float*)d_ws;   // N*T floats = 16.8 MB workspace
    const size_t SNT = (size_t)S_ * N_ * T_;

    k_drive<<<(N_ * T_) / 256, 256, 0, stream>>>(A, L, V, Y, gA, gLw, gVw,
                                                 alpha, mu_i, c);
    k_fill_lv<<<(int)(SNT / 4 / 256), 256, 0, stream>>>(lsig, lsig0,
                                                        out + 2 * SNT);
    k_scan<<<N_ / 64, 256, 0, stream>>>(c, eps, psi, lsig, lsig0, out);
}